// Round 1
// baseline (822.314 us; speedup 1.0000x reference)
//
#include <hip/hip_runtime.h>
#include <stdint.h>

typedef unsigned short u16;
typedef __bf16 bf16x8 __attribute__((ext_vector_type(8)));
typedef float f32x4 __attribute__((ext_vector_type(4)));

__device__ __forceinline__ u16 f2bf(float f) {
  union { float f; uint32_t u; } v; v.f = f;
  return (u16)((v.u + 0x7FFFu + ((v.u >> 16) & 1u)) >> 16);
}
__device__ __forceinline__ float bf2f(u16 u) {
  union { uint32_t u; float f; } v; v.u = ((uint32_t)u) << 16;
  return v.f;
}
__device__ __forceinline__ float gelu_tanh(float x) {
  float t = tanhf(0.7978845608028654f * (x + 0.044715f * x * x * x));
  return 0.5f * x * (1.0f + t);
}

// ---------------- K0: prep: W_down -> bf16 [n=64][k=1024], W_up -> bf16 [n=1024][k=64], nq ----
__global__ __launch_bounds__(256) void k0_prep(const float* __restrict__ Wd,
                                               const float* __restrict__ Wu,
                                               const float* __restrict__ mq,
                                               u16* __restrict__ WdT, u16* __restrict__ WuT,
                                               float* __restrict__ nq) {
  int b = blockIdx.x, t = threadIdx.x;
  if (b < 256) {
    int e = b * 256 + t;                 // 0..65535
    int n = e >> 10, k = e & 1023;       // WdT[n][k] = Wd[k][n]
    WdT[e] = f2bf(Wd[k * 64 + n]);
    int n2 = e >> 6, k2 = e & 63;        // WuT[n][k] = Wu[k][n]
    WuT[e] = f2bf(Wu[k2 * 1024 + n2]);
  } else {
    if (t < 16) {
      float ss = 0.f;
      for (int c = 0; c < 64; c++) { float v = mq[t * 64 + c]; ss += v * v; }
      float inv = 1.0f / (sqrtf(ss) + 1e-12f);
      for (int c = 0; c < 64; c++) nq[t * 64 + c] = mq[t * 64 + c] * inv;
    }
  }
}

// ---------------- K1: act = gelu(X @ W_down + b_down); scores = max_m cos(act, nq_m) ----------
__global__ __launch_bounds__(256) void k1_gemm_down(const float* __restrict__ feat,
                                                    const u16* __restrict__ WdT,
                                                    const float* __restrict__ b_down,
                                                    const float* __restrict__ nq_g,
                                                    float* __restrict__ act,
                                                    float* __restrict__ scores) {
  __shared__ __align__(16) u16 Asm[64 * 72];   // [row][k] pad 72
  __shared__ __align__(16) u16 Bsm[64 * 72];   // [n][k]  pad 72
  __shared__ float acts[64 * 65];              // [row][col] pad 65
  __shared__ float nqs[16 * 64];
  int t = threadIdx.x;
  int lane = t & 63, w = t >> 6;
  int l15 = lane & 15, q = lane >> 4;
  long r0 = (long)blockIdx.x * 64;

  for (int i = t; i < 1024; i += 256) nqs[i] = nq_g[i];

  f32x4 acc[4] = {};
  int rloc = t >> 4;          // 0..15
  int col4 = (t & 15) * 4;    // 0..60
  int nB = t >> 2;            // 0..63
  int cB = t & 3;

  for (int kt = 0; kt < 16; kt++) {
    int k0 = kt * 64;
    __syncthreads();
    // stage A: 64 rows x 64 k (fp32 -> bf16)
    for (int p = 0; p < 4; p++) {
      int row = p * 16 + rloc;
      const float4 v = *(const float4*)&feat[(r0 + row) * 1024 + k0 + col4];
      ushort4 u; u.x = f2bf(v.x); u.y = f2bf(v.y); u.z = f2bf(v.z); u.w = f2bf(v.w);
      *(ushort4*)&Asm[row * 72 + col4] = u;
    }
    // stage B: 64 n x 64 k (already bf16, [n][k] layout)
    for (int h = 0; h < 2; h++) {
      int c = cB + h * 4;  // chunk of 8 bf16
      *(uint4*)&Bsm[nB * 72 + c * 8] = *(const uint4*)&WdT[nB * 1024 + k0 + c * 8];
    }
    __syncthreads();
    for (int ks = 0; ks < 2; ks++) {
      bf16x8 a = *(bf16x8*)&Asm[(w * 16 + l15) * 72 + ks * 32 + q * 8];
#pragma unroll
      for (int tn = 0; tn < 4; tn++) {
        bf16x8 bb = *(bf16x8*)&Bsm[(tn * 16 + l15) * 72 + ks * 32 + q * 8];
        acc[tn] = __builtin_amdgcn_mfma_f32_16x16x32_bf16(a, bb, acc[tn], 0, 0, 0);
      }
    }
  }
  // epilogue: bias + gelu, write act (global) + acts (LDS)
#pragma unroll
  for (int tn = 0; tn < 4; tn++) {
    int col = tn * 16 + l15;
    float bd = b_down[col];
#pragma unroll
    for (int j = 0; j < 4; j++) {
      int row = w * 16 + q * 4 + j;
      float g = gelu_tanh(acc[tn][j] + bd);
      act[(r0 + row) * 64 + col] = g;
      acts[row * 65 + col] = g;
    }
  }
  __syncthreads();
  // scores: 4 threads per row
  {
    int r = t >> 2, p = t & 3;
    float ss = 0.f;
    float dots[16];
#pragma unroll
    for (int m = 0; m < 16; m++) dots[m] = 0.f;
    for (int i = 0; i < 16; i++) {
      int c = p * 16 + i;
      float v = acts[r * 65 + c];
      ss += v * v;
#pragma unroll
      for (int m = 0; m < 16; m++) dots[m] += v * nqs[m * 64 + c];
    }
    ss += __shfl_xor(ss, 1); ss += __shfl_xor(ss, 2);
#pragma unroll
    for (int m = 0; m < 16; m++) {
      dots[m] += __shfl_xor(dots[m], 1);
      dots[m] += __shfl_xor(dots[m], 2);
    }
    if (p == 0) {
      float inv = 1.0f / (sqrtf(ss) + 1e-12f);
      float best = -INFINITY;
#pragma unroll
      for (int m = 0; m < 16; m++) best = fmaxf(best, dots[m] * inv);
      scores[r0 + r] = best;
    }
  }
}

// ---------------- K2: per-batch top-64 (iterative argmax, ties -> lowest index), sorted -------
__global__ __launch_bounds__(256) void k2_topk(const float* __restrict__ scores,
                                               int* __restrict__ idx_out) {
  __shared__ float s[4096];
  __shared__ float wv[4];
  __shared__ int wi[4];
  __shared__ int list[64];
  __shared__ int slist[64];
  int b = blockIdx.x, t = threadIdx.x;
  for (int i = t; i < 4096; i += 256) s[i] = scores[b * 4096 + i];
  __syncthreads();
  for (int sel = 0; sel < 64; sel++) {
    float bv = -INFINITY; int bi = 0x7fffffff;
    for (int i = t; i < 4096; i += 256) {
      float v = s[i];
      if (v > bv || (v == bv && i < bi)) { bv = v; bi = i; }
    }
    for (int m = 1; m < 64; m <<= 1) {
      float ov = __shfl_xor(bv, m); int oi = __shfl_xor(bi, m);
      if (ov > bv || (ov == bv && oi < bi)) { bv = ov; bi = oi; }
    }
    if ((t & 63) == 0) { wv[t >> 6] = bv; wi[t >> 6] = bi; }
    __syncthreads();
    if (t == 0) {
      float fv = wv[0]; int fi = wi[0];
      for (int u2 = 1; u2 < 4; u2++)
        if (wv[u2] > fv || (wv[u2] == fv && wi[u2] < fi)) { fv = wv[u2]; fi = wi[u2]; }
      list[sel] = fi;
      s[fi] = -INFINITY;
    }
    __syncthreads();
  }
  if (t < 64) {
    int v = list[t], rank = 0;
    for (int j = 0; j < 64; j++) rank += (list[j] < v);
    slist[rank] = v;
  }
  __syncthreads();
  if (t < 64) idx_out[b * 64 + t] = slist[t];
}

// ---------------- K3a: gather + layernorm + QKV projection ----------------------------------
__global__ __launch_bounds__(256) void k3a_ln_qkv(const float* __restrict__ act,
                                                  const float* __restrict__ mq,
                                                  const int* __restrict__ idx,
                                                  const float* __restrict__ lnw,
                                                  const float* __restrict__ lnb,
                                                  const float* __restrict__ inw,
                                                  const float* __restrict__ inb,
                                                  float* __restrict__ qkv) {
  __shared__ float xs[80 * 65];     // pad 65
  __shared__ u16 wsm[192 * 66];     // in_proj_w bf16, pad 66
  __shared__ int ii[64];
  int b = blockIdx.x, t = threadIdx.x;
  if (t < 64) ii[t] = idx[b * 64 + t];
  for (int e = t; e < 192 * 32; e += 256) {  // pack 2 bf16 per dword write
    int j = e >> 5, cp = e & 31;
    uint32_t pk = (uint32_t)f2bf(inw[j * 64 + cp * 2]) |
                  ((uint32_t)f2bf(inw[j * 64 + cp * 2 + 1]) << 16);
    *(uint32_t*)&wsm[j * 66 + cp * 2] = pk;
  }
  __syncthreads();
  for (int e = t; e < 80 * 64; e += 256) {
    int r = e >> 6, c = e & 63;
    xs[r * 65 + c] = (r < 16) ? mq[r * 64 + c]
                              : act[((long)b * 4096 + ii[r - 16]) * 64 + c];
  }
  __syncthreads();
  if (t < 80) {
    float mu = 0.f;
    for (int c = 0; c < 64; c++) mu += xs[t * 65 + c];
    mu *= (1.0f / 64.0f);
    float var = 0.f;
    for (int c = 0; c < 64; c++) { float d = xs[t * 65 + c] - mu; var += d * d; }
    var *= (1.0f / 64.0f);
    float rs = 1.0f / sqrtf(var + 1e-5f);
    for (int c = 0; c < 64; c++)
      xs[t * 65 + c] = (xs[t * 65 + c] - mu) * rs * lnw[c] + lnb[c];
  }
  __syncthreads();
  for (int e = t; e < 80 * 192; e += 256) {
    int i = e / 192, j = e % 192;
    float s = inb[j];
    for (int d = 0; d < 64; d++) s += xs[i * 65 + d] * bf2f(wsm[j * 66 + d]);
    qkv[((long)b * 80 + i) * 192 + j] = s;
  }
}

// ---------------- K3b: attention per (batch, head) -------------------------------------------
__global__ __launch_bounds__(256) void k3b_attn(const float* __restrict__ qkv,
                                                float* __restrict__ attn_o) {
  __shared__ float qs[80 * 17], kk[80 * 17], vs[80 * 17];  // pad 17
  __shared__ float ps[80 * 81];                            // pad 81
  int blk = blockIdx.x; int b = blk >> 2, h = blk & 3;
  int t = threadIdx.x;
  for (int e = t; e < 80 * 16; e += 256) {
    int i = e >> 4, d = e & 15;
    const float* base = &qkv[((long)b * 80 + i) * 192 + h * 16 + d];
    qs[i * 17 + d] = base[0];
    kk[i * 17 + d] = base[64];
    vs[i * 17 + d] = base[128];
  }
  __syncthreads();
  for (int e = t; e < 80 * 80; e += 256) {
    int i = e / 80, j = e % 80;
    float s = 0.f;
#pragma unroll
    for (int d = 0; d < 16; d++) s += qs[i * 17 + d] * kk[j * 17 + d];
    ps[i * 81 + j] = s * 0.25f;
  }
  __syncthreads();
  if (t < 80) {
    float mx = -INFINITY;
    for (int j = 0; j < 80; j++) mx = fmaxf(mx, ps[t * 81 + j]);
    float sum = 0.f;
    for (int j = 0; j < 80; j++) { float e2 = expf(ps[t * 81 + j] - mx); ps[t * 81 + j] = e2; sum += e2; }
    float inv = 1.0f / sum;
    for (int j = 0; j < 80; j++) ps[t * 81 + j] *= inv;
  }
  __syncthreads();
  for (int e = t; e < 80 * 16; e += 256) {
    int i = e >> 4, d = e & 15;
    float s = 0.f;
    for (int j = 0; j < 80; j++) s += ps[i * 81 + j] * vs[j * 17 + d];
    attn_o[((long)b * 80 + i) * 64 + h * 16 + d] = s;
  }
}

// ---------------- K3c: out-proj rows 16..79, scatter into act at idx --------------------------
__global__ __launch_bounds__(256) void k3c_outproj(const float* __restrict__ attn_o,
                                                   const float* __restrict__ ow,
                                                   const float* __restrict__ ob,
                                                   const int* __restrict__ idx,
                                                   float* __restrict__ act) {
  __shared__ float os[64 * 64];
  __shared__ float wsm[64 * 65];  // pad 65
  __shared__ int ii[64];
  int b = blockIdx.x, t = threadIdx.x;
  if (t < 64) ii[t] = idx[b * 64 + t];
  for (int e = t; e < 4096; e += 256) {
    int r = e >> 6, c = e & 63;
    os[e] = attn_o[((long)b * 80 + 16 + r) * 64 + c];
    wsm[r * 65 + c] = ow[e];
  }
  __syncthreads();
  for (int e = t; e < 4096; e += 256) {
    int r = e >> 6, j = e & 63;
    float s = ob[j];
    for (int d = 0; d < 64; d++) s += os[r * 64 + d] * wsm[j * 65 + d];
    act[((long)b * 4096 + ii[r]) * 64 + j] = s;
  }
}

// ---------------- K4: out = identity + gamma * (act @ W_up + b_up) ----------------------------
__global__ __launch_bounds__(256) void k4_gemm_up(const float* __restrict__ act,
                                                  const u16* __restrict__ WuT,
                                                  const float* __restrict__ identity,
                                                  const float* __restrict__ b_up,
                                                  const float* __restrict__ gamma,
                                                  float* __restrict__ out) {
  __shared__ __align__(16) u16 Asm[64 * 72];    // [row][k] pad 72
  __shared__ __align__(16) u16 Bsm[256 * 72];   // [n][k] pad 72
  int t = threadIdx.x;
  int lane = t & 63, w = t >> 6;
  int l15 = lane & 15, q = lane >> 4;
  int bx = blockIdx.x;
  long r0 = (long)(bx >> 2) * 64;
  int n0 = (bx & 3) * 256;

  {
    int col4 = (t & 15) * 4;
    int rloc = t >> 4;
    for (int p = 0; p < 4; p++) {
      int row = p * 16 + rloc;
      float4 v = *(const float4*)&act[(r0 + row) * 64 + col4];
      ushort4 u; u.x = f2bf(v.x); u.y = f2bf(v.y); u.z = f2bf(v.z); u.w = f2bf(v.w);
      *(ushort4*)&Asm[row * 72 + col4] = u;
    }
  }
  for (int c = 0; c < 8; c++)
    *(uint4*)&Bsm[t * 72 + c * 8] = *(const uint4*)&WuT[(n0 + t) * 64 + c * 8];
  __syncthreads();

  f32x4 acc[16] = {};
  for (int ks = 0; ks < 2; ks++) {
    bf16x8 a = *(bf16x8*)&Asm[(w * 16 + l15) * 72 + ks * 32 + q * 8];
#pragma unroll
    for (int tn = 0; tn < 16; tn++) {
      bf16x8 bb = *(bf16x8*)&Bsm[(tn * 16 + l15) * 72 + ks * 32 + q * 8];
      acc[tn] = __builtin_amdgcn_mfma_f32_16x16x32_bf16(a, bb, acc[tn], 0, 0, 0);
    }
  }
  float g = gamma[0];
#pragma unroll
  for (int tn = 0; tn < 16; tn++) {
    int col = n0 + tn * 16 + l15;
    float bu = b_up[col];
#pragma unroll
    for (int j = 0; j < 4; j++) {
      long row = r0 + w * 16 + q * 4 + j;
      long off = row * 1024 + col;
      out[off] = identity[off] + g * (acc[tn][j] + bu);
    }
  }
}

extern "C" void kernel_launch(void* const* d_in, const int* in_sizes, int n_in,
                              void* d_out, int out_size, void* d_ws, size_t ws_size,
                              hipStream_t stream) {
  const float* feat = (const float*)d_in[0];
  const float* Wd   = (const float*)d_in[1];
  const float* bd   = (const float*)d_in[2];
  const float* Wu   = (const float*)d_in[3];
  const float* bu   = (const float*)d_in[4];
  const float* mq   = (const float*)d_in[5];
  const float* lnw  = (const float*)d_in[6];
  const float* lnb  = (const float*)d_in[7];
  const float* inw  = (const float*)d_in[8];
  const float* inb  = (const float*)d_in[9];
  const float* ow   = (const float*)d_in[10];
  const float* ob   = (const float*)d_in[11];
  const float* gm   = (const float*)d_in[12];
  float* out = (float*)d_out;
  char* ws = (char*)d_ws;

  float* act    = (float*)(ws + 0);          // 16,777,216 B
  float* scores = (float*)(ws + 16777216);   //    262,144 B
  u16*   WdT    = (u16*)  (ws + 17039360);   //    131,072 B
  u16*   WuT    = (u16*)  (ws + 17170432);   //    131,072 B
  float* nq     = (float*)(ws + 17301504);   //      4,096 B
  int*   idx    = (int*)  (ws + 17305600);   //      4,096 B
  float* qkv    = (float*)(ws + 17309696);   //    983,040 B
  float* ao     = (float*)(ws + 18292736);   //    327,680 B  (total 18,620,416)

  hipLaunchKernelGGL(k0_prep,     dim3(257),  dim3(256), 0, stream, Wd, Wu, mq, WdT, WuT, nq);
  hipLaunchKernelGGL(k1_gemm_down,dim3(1024), dim3(256), 0, stream, feat, WdT, bd, nq, act, scores);
  hipLaunchKernelGGL(k2_topk,     dim3(16),   dim3(256), 0, stream, scores, idx);
  hipLaunchKernelGGL(k3a_ln_qkv,  dim3(16),   dim3(256), 0, stream, act, mq, idx, lnw, lnb, inw, inb, qkv);
  hipLaunchKernelGGL(k3b_attn,    dim3(64),   dim3(256), 0, stream, qkv, ao);
  hipLaunchKernelGGL(k3c_outproj, dim3(16),   dim3(256), 0, stream, ao, ow, ob, idx, act);
  hipLaunchKernelGGL(k4_gemm_up,  dim3(4096), dim3(256), 0, stream, act, WuT, feat, bu, gm, out);
}

// Round 2
// 746.422 us; speedup vs baseline: 1.1017x; 1.1017x over previous
//
#include <hip/hip_runtime.h>
#include <stdint.h>

typedef unsigned short u16;
typedef __bf16 bf16x8 __attribute__((ext_vector_type(8)));
typedef float f32x4 __attribute__((ext_vector_type(4)));

__device__ __forceinline__ u16 f2bf(float f) {
  union { float f; uint32_t u; } v; v.f = f;
  return (u16)((v.u + 0x7FFFu + ((v.u >> 16) & 1u)) >> 16);
}
__device__ __forceinline__ float bf2f(u16 u) {
  union { uint32_t u; float f; } v; v.u = ((uint32_t)u) << 16;
  return v.f;
}
__device__ __forceinline__ float gelu_tanh(float x) {
  float t = tanhf(0.7978845608028654f * (x + 0.044715f * x * x * x));
  return 0.5f * x * (1.0f + t);
}

// ---------------- K0: prep: W_down -> bf16 [n=64][k=1024], W_up -> bf16 [n=1024][k=64], nq ----
__global__ __launch_bounds__(256) void k0_prep(const float* __restrict__ Wd,
                                               const float* __restrict__ Wu,
                                               const float* __restrict__ mq,
                                               u16* __restrict__ WdT, u16* __restrict__ WuT,
                                               float* __restrict__ nq) {
  int b = blockIdx.x, t = threadIdx.x;
  if (b < 256) {
    int e = b * 256 + t;                 // 0..65535
    int n = e >> 10, k = e & 1023;       // WdT[n][k] = Wd[k][n]
    WdT[e] = f2bf(Wd[k * 64 + n]);
    int n2 = e >> 6, k2 = e & 63;        // WuT[n][k] = Wu[k][n]
    WuT[e] = f2bf(Wu[k2 * 1024 + n2]);
  } else {
    if (t < 16) {
      float ss = 0.f;
      for (int c = 0; c < 64; c++) { float v = mq[t * 64 + c]; ss += v * v; }
      float inv = 1.0f / (sqrtf(ss) + 1e-12f);
      for (int c = 0; c < 64; c++) nq[t * 64 + c] = mq[t * 64 + c] * inv;
    }
  }
}

// ---------------- K1: act = gelu(X @ W_down + b_down); scores = max_m cos(act, nq_m) ----------
// software-pipelined: global loads of tile kt+1 overlap MFMA on tile kt
__global__ __launch_bounds__(256) void k1_gemm_down(const float* __restrict__ feat,
                                                    const u16* __restrict__ WdT,
                                                    const float* __restrict__ b_down,
                                                    const float* __restrict__ nq_g,
                                                    float* __restrict__ act,
                                                    float* __restrict__ scores) {
  __shared__ __align__(16) u16 Asm[64 * 72];   // [row][k] pad 72
  __shared__ __align__(16) u16 Bsm[64 * 72];   // [n][k]  pad 72
  __shared__ float acts[64 * 65];              // [row][col] pad 65
  __shared__ float nqs[16 * 64];
  int t = threadIdx.x;
  int lane = t & 63, w = t >> 6;
  int l15 = lane & 15, q = lane >> 4;
  long r0 = (long)blockIdx.x * 64;

  for (int i = t; i < 1024; i += 256) nqs[i] = nq_g[i];

  f32x4 acc[4] = {};
  int rloc = t >> 4;          // 0..15
  int col4 = (t & 15) * 4;    // 0..60
  int nB = t >> 2;            // 0..63
  int cB = t & 3;

  float4 aReg[4];
  uint4 bReg[2];
  // preload tile 0
#pragma unroll
  for (int p = 0; p < 4; p++)
    aReg[p] = *(const float4*)&feat[(r0 + p * 16 + rloc) * 1024 + col4];
#pragma unroll
  for (int h = 0; h < 2; h++)
    bReg[h] = *(const uint4*)&WdT[nB * 1024 + (cB + h * 4) * 8];

  for (int kt = 0; kt < 16; kt++) {
    // regs -> LDS
#pragma unroll
    for (int p = 0; p < 4; p++) {
      ushort4 u; u.x = f2bf(aReg[p].x); u.y = f2bf(aReg[p].y);
      u.z = f2bf(aReg[p].z); u.w = f2bf(aReg[p].w);
      *(ushort4*)&Asm[(p * 16 + rloc) * 72 + col4] = u;
    }
#pragma unroll
    for (int h = 0; h < 2; h++)
      *(uint4*)&Bsm[nB * 72 + (cB + h * 4) * 8] = bReg[h];
    __syncthreads();
    // prefetch next tile (overlaps MFMA below)
    if (kt < 15) {
      int k0 = (kt + 1) * 64;
#pragma unroll
      for (int p = 0; p < 4; p++)
        aReg[p] = *(const float4*)&feat[(r0 + p * 16 + rloc) * 1024 + k0 + col4];
#pragma unroll
      for (int h = 0; h < 2; h++)
        bReg[h] = *(const uint4*)&WdT[nB * 1024 + k0 + (cB + h * 4) * 8];
    }
#pragma unroll
    for (int ks = 0; ks < 2; ks++) {
      bf16x8 a = *(bf16x8*)&Asm[(w * 16 + l15) * 72 + ks * 32 + q * 8];
#pragma unroll
      for (int tn = 0; tn < 4; tn++) {
        bf16x8 bb = *(bf16x8*)&Bsm[(tn * 16 + l15) * 72 + ks * 32 + q * 8];
        acc[tn] = __builtin_amdgcn_mfma_f32_16x16x32_bf16(a, bb, acc[tn], 0, 0, 0);
      }
    }
    __syncthreads();
  }
  // epilogue: bias + gelu, write act (global) + acts (LDS)
#pragma unroll
  for (int tn = 0; tn < 4; tn++) {
    int col = tn * 16 + l15;
    float bd = b_down[col];
#pragma unroll
    for (int j = 0; j < 4; j++) {
      int row = w * 16 + q * 4 + j;
      float g = gelu_tanh(acc[tn][j] + bd);
      act[(r0 + row) * 64 + col] = g;
      acts[row * 65 + col] = g;
    }
  }
  __syncthreads();
  // scores: 4 threads per row
  {
    int r = t >> 2, p = t & 3;
    float ss = 0.f;
    float dots[16];
#pragma unroll
    for (int m = 0; m < 16; m++) dots[m] = 0.f;
    for (int i = 0; i < 16; i++) {
      int c = p * 16 + i;
      float v = acts[r * 65 + c];
      ss += v * v;
#pragma unroll
      for (int m = 0; m < 16; m++) dots[m] += v * nqs[m * 64 + c];
    }
    ss += __shfl_xor(ss, 1); ss += __shfl_xor(ss, 2);
#pragma unroll
    for (int m = 0; m < 16; m++) {
      dots[m] += __shfl_xor(dots[m], 1);
      dots[m] += __shfl_xor(dots[m], 2);
    }
    if (p == 0) {
      float inv = 1.0f / (sqrtf(ss) + 1e-12f);
      float best = -INFINITY;
#pragma unroll
      for (int m = 0; m < 16; m++) best = fmaxf(best, dots[m] * inv);
      scores[r0 + r] = best;
    }
  }
}

// ---------------- K2: per-batch top-64 (iterative argmax, ties -> lowest index), sorted -------
__global__ __launch_bounds__(256) void k2_topk(const float* __restrict__ scores,
                                               int* __restrict__ idx_out) {
  __shared__ float s[4096];
  __shared__ float wv[4];
  __shared__ int wi[4];
  __shared__ int list[64];
  __shared__ int slist[64];
  int b = blockIdx.x, t = threadIdx.x;
  for (int i = t; i < 4096; i += 256) s[i] = scores[b * 4096 + i];
  __syncthreads();
  for (int sel = 0; sel < 64; sel++) {
    float bv = -INFINITY; int bi = 0x7fffffff;
    for (int i = t; i < 4096; i += 256) {
      float v = s[i];
      if (v > bv || (v == bv && i < bi)) { bv = v; bi = i; }
    }
    for (int m = 1; m < 64; m <<= 1) {
      float ov = __shfl_xor(bv, m); int oi = __shfl_xor(bi, m);
      if (ov > bv || (ov == bv && oi < bi)) { bv = ov; bi = oi; }
    }
    if ((t & 63) == 0) { wv[t >> 6] = bv; wi[t >> 6] = bi; }
    __syncthreads();
    if (t == 0) {
      float fv = wv[0]; int fi = wi[0];
      for (int u2 = 1; u2 < 4; u2++)
        if (wv[u2] > fv || (wv[u2] == fv && wi[u2] < fi)) { fv = wv[u2]; fi = wi[u2]; }
      list[sel] = fi;
      s[fi] = -INFINITY;
    }
    __syncthreads();
  }
  if (t < 64) {
    int v = list[t], rank = 0;
    for (int j = 0; j < 64; j++) rank += (list[j] < v);
    slist[rank] = v;
  }
  __syncthreads();
  if (t < 64) idx_out[b * 64 + t] = slist[t];
}

// ---------------- K3a: gather + layernorm + QKV projection (MFMA) ----------------------------
__global__ __launch_bounds__(256) void k3a_ln_qkv(const float* __restrict__ act,
                                                  const float* __restrict__ mq,
                                                  const int* __restrict__ idx,
                                                  const float* __restrict__ lnw,
                                                  const float* __restrict__ lnb,
                                                  const float* __restrict__ inw,
                                                  const float* __restrict__ inb,
                                                  float* __restrict__ qkv) {
  __shared__ float xs[80 * 65];        // fp32 gathered rows
  __shared__ __align__(16) u16 xsb[80 * 72];   // LN'd bf16 A [m][k]
  __shared__ __align__(16) u16 wb[192 * 72];   // in_proj_w bf16 B [n][k]
  __shared__ int ii[64];
  int b = blockIdx.x, t = threadIdx.x;
  if (t < 64) ii[t] = idx[b * 64 + t];
  for (int e = t; e < 192 * 64; e += 256) {
    int j = e >> 6, d = e & 63;
    wb[j * 72 + d] = f2bf(inw[e]);
  }
  __syncthreads();
  for (int e = t; e < 80 * 64; e += 256) {
    int r = e >> 6, c = e & 63;
    xs[r * 65 + c] = (r < 16) ? mq[e]
                              : act[((long)b * 4096 + ii[r - 16]) * 64 + c];
  }
  __syncthreads();
  // LN: 2 threads per row
  if (t < 160) {
    int r = t >> 1, p = t & 1;
    float s1 = 0.f, s2 = 0.f;
    for (int c = p * 32; c < p * 32 + 32; c++) {
      float v = xs[r * 65 + c]; s1 += v; s2 += v * v;
    }
    s1 += __shfl_xor(s1, 1); s2 += __shfl_xor(s2, 1);
    float mu = s1 * (1.0f / 64.0f);
    float var = s2 * (1.0f / 64.0f) - mu * mu;
    float rs = 1.0f / sqrtf(var + 1e-5f);
    for (int c = p * 32; c < p * 32 + 32; c++) {
      float v = (xs[r * 65 + c] - mu) * rs * lnw[c] + lnb[c];
      xsb[r * 72 + c] = f2bf(v);
    }
  }
  __syncthreads();
  // MFMA: wave w handles n-tiles 3w..3w+2, all 5 m-tiles (80 = 5*16)
  int lane = t & 63, w = t >> 6, l15 = lane & 15, q = lane >> 4;
  f32x4 acc[15] = {};
#pragma unroll
  for (int m = 0; m < 5; m++) {
    bf16x8 a0 = *(bf16x8*)&xsb[(m * 16 + l15) * 72 + q * 8];
    bf16x8 a1 = *(bf16x8*)&xsb[(m * 16 + l15) * 72 + 32 + q * 8];
#pragma unroll
    for (int nn = 0; nn < 3; nn++) {
      int n = w * 3 + nn;
      bf16x8 b0 = *(bf16x8*)&wb[(n * 16 + l15) * 72 + q * 8];
      bf16x8 b1 = *(bf16x8*)&wb[(n * 16 + l15) * 72 + 32 + q * 8];
      acc[m * 3 + nn] = __builtin_amdgcn_mfma_f32_16x16x32_bf16(a0, b0, acc[m * 3 + nn], 0, 0, 0);
      acc[m * 3 + nn] = __builtin_amdgcn_mfma_f32_16x16x32_bf16(a1, b1, acc[m * 3 + nn], 0, 0, 0);
    }
  }
#pragma unroll
  for (int m = 0; m < 5; m++)
#pragma unroll
    for (int nn = 0; nn < 3; nn++) {
      int j = (w * 3 + nn) * 16 + l15;
      float bias = inb[j];
#pragma unroll
      for (int jj = 0; jj < 4; jj++) {
        int i = m * 16 + q * 4 + jj;
        qkv[((long)b * 80 + i) * 192 + j] = acc[m * 3 + nn][jj] + bias;
      }
    }
}

// ---------------- K3b: attention per (batch, head) -------------------------------------------
__global__ __launch_bounds__(256) void k3b_attn(const float* __restrict__ qkv,
                                                float* __restrict__ attn_o) {
  __shared__ float qs[80 * 17], kk[80 * 17], vs[80 * 17];  // pad 17
  __shared__ float ps[80 * 81];                            // pad 81
  int blk = blockIdx.x; int b = blk >> 2, h = blk & 3;
  int t = threadIdx.x;
  for (int e = t; e < 80 * 16; e += 256) {
    int i = e >> 4, d = e & 15;
    const float* base = &qkv[((long)b * 80 + i) * 192 + h * 16 + d];
    qs[i * 17 + d] = base[0];
    kk[i * 17 + d] = base[64];
    vs[i * 17 + d] = base[128];
  }
  __syncthreads();
  for (int e = t; e < 80 * 80; e += 256) {
    int i = e / 80, j = e % 80;
    float s = 0.f;
#pragma unroll
    for (int d = 0; d < 16; d++) s += qs[i * 17 + d] * kk[j * 17 + d];
    ps[i * 81 + j] = s * 0.25f;
  }
  __syncthreads();
  if (t < 80) {
    float mx = -INFINITY;
    for (int j = 0; j < 80; j++) mx = fmaxf(mx, ps[t * 81 + j]);
    float sum = 0.f;
    for (int j = 0; j < 80; j++) { float e2 = expf(ps[t * 81 + j] - mx); ps[t * 81 + j] = e2; sum += e2; }
    float inv = 1.0f / sum;
    for (int j = 0; j < 80; j++) ps[t * 81 + j] *= inv;
  }
  __syncthreads();
  for (int e = t; e < 80 * 16; e += 256) {
    int i = e >> 4, d = e & 15;
    float s = 0.f;
    for (int j = 0; j < 80; j++) s += ps[i * 81 + j] * vs[j * 17 + d];
    attn_o[((long)b * 80 + i) * 64 + h * 16 + d] = s;
  }
}

// ---------------- K3c: out-proj rows 16..79 (MFMA), scatter into act at idx ------------------
__global__ __launch_bounds__(256) void k3c_outproj(const float* __restrict__ attn_o,
                                                   const float* __restrict__ ow,
                                                   const float* __restrict__ ob,
                                                   const int* __restrict__ idx,
                                                   float* __restrict__ act) {
  __shared__ __align__(16) u16 osb[64 * 72];  // A: enhanced rows bf16
  __shared__ __align__(16) u16 wbb[64 * 72];  // B: ow [j][d] bf16
  __shared__ int ii[64];
  int b = blockIdx.x, t = threadIdx.x;
  if (t < 64) ii[t] = idx[b * 64 + t];
  for (int e = t; e < 4096; e += 256) {
    int r = e >> 6, c = e & 63;
    osb[r * 72 + c] = f2bf(attn_o[((long)b * 80 + 16 + r) * 64 + c]);
    wbb[r * 72 + c] = f2bf(ow[e]);
  }
  __syncthreads();
  int lane = t & 63, w = t >> 6, l15 = lane & 15, q = lane >> 4;
  f32x4 acc[4] = {};
  bf16x8 b0 = *(bf16x8*)&wbb[(w * 16 + l15) * 72 + q * 8];
  bf16x8 b1 = *(bf16x8*)&wbb[(w * 16 + l15) * 72 + 32 + q * 8];
#pragma unroll
  for (int m = 0; m < 4; m++) {
    bf16x8 a0 = *(bf16x8*)&osb[(m * 16 + l15) * 72 + q * 8];
    bf16x8 a1 = *(bf16x8*)&osb[(m * 16 + l15) * 72 + 32 + q * 8];
    acc[m] = __builtin_amdgcn_mfma_f32_16x16x32_bf16(a0, b0, acc[m], 0, 0, 0);
    acc[m] = __builtin_amdgcn_mfma_f32_16x16x32_bf16(a1, b1, acc[m], 0, 0, 0);
  }
  int j = w * 16 + l15;
  float bias = ob[j];
#pragma unroll
  for (int m = 0; m < 4; m++)
#pragma unroll
    for (int jj = 0; jj < 4; jj++) {
      int r = m * 16 + q * 4 + jj;
      act[((long)b * 4096 + ii[r]) * 64 + j] = acc[m][jj] + bias;
    }
}

// ---------------- K4: out = identity + gamma * (act @ W_up + b_up) ----------------------------
// epilogue bounced through LDS for float4 identity/out traffic
__global__ __launch_bounds__(256) void k4_gemm_up(const float* __restrict__ act,
                                                  const u16* __restrict__ WuT,
                                                  const float* __restrict__ identity,
                                                  const float* __restrict__ b_up,
                                                  const float* __restrict__ gamma,
                                                  float* __restrict__ out) {
  __shared__ __align__(16) u16 Asm[64 * 72];    // [row][k] pad 72
  __shared__ __align__(16) u16 Bsm[256 * 72];   // [n][k] pad 72 (reused as Csm)
  float* Csm = (float*)Bsm;                     // 64 x 68 fp32 chunk staging
  int t = threadIdx.x;
  int lane = t & 63, w = t >> 6;
  int l15 = lane & 15, q = lane >> 4;
  int bx = blockIdx.x;
  long r0 = (long)(bx >> 2) * 64;
  int n0 = (bx & 3) * 256;

  {
    int col4 = (t & 15) * 4;
    int rloc = t >> 4;
    for (int p = 0; p < 4; p++) {
      int row = p * 16 + rloc;
      float4 v = *(const float4*)&act[(r0 + row) * 64 + col4];
      ushort4 u; u.x = f2bf(v.x); u.y = f2bf(v.y); u.z = f2bf(v.z); u.w = f2bf(v.w);
      *(ushort4*)&Asm[row * 72 + col4] = u;
    }
  }
  for (int c = 0; c < 8; c++)
    *(uint4*)&Bsm[t * 72 + c * 8] = *(const uint4*)&WuT[(n0 + t) * 64 + c * 8];
  __syncthreads();

  f32x4 acc[16] = {};
#pragma unroll
  for (int ks = 0; ks < 2; ks++) {
    bf16x8 a = *(bf16x8*)&Asm[(w * 16 + l15) * 72 + ks * 32 + q * 8];
#pragma unroll
    for (int tn = 0; tn < 16; tn++) {
      bf16x8 bb = *(bf16x8*)&Bsm[(tn * 16 + l15) * 72 + ks * 32 + q * 8];
      acc[tn] = __builtin_amdgcn_mfma_f32_16x16x32_bf16(a, bb, acc[tn], 0, 0, 0);
    }
  }
  float g = gamma[0];
  int rdrow = t >> 4;            // 0..15
  int rdcol4 = (t & 15) * 4;     // 0..60
#pragma unroll
  for (int c = 0; c < 4; c++) {
    __syncthreads();   // Bsm/Csm free (MFMA done / previous chunk consumed)
#pragma unroll
    for (int u2 = 0; u2 < 4; u2++) {
      int tn = c * 4 + u2;
      int lc = u2 * 16 + l15;
      float bias = b_up[n0 + c * 64 + lc];
#pragma unroll
      for (int jj = 0; jj < 4; jj++) {
        int row = w * 16 + q * 4 + jj;
        Csm[row * 68 + lc] = acc[tn][jj] + bias;
      }
    }
    __syncthreads();
#pragma unroll
    for (int p = 0; p < 4; p++) {
      int row = p * 16 + rdrow;
      long off = (r0 + row) * 1024 + n0 + c * 64 + rdcol4;
      float4 cv = *(float4*)&Csm[row * 68 + rdcol4];
      float4 iv = *(const float4*)&identity[off];
      float4 ov;
      ov.x = iv.x + g * cv.x; ov.y = iv.y + g * cv.y;
      ov.z = iv.z + g * cv.z; ov.w = iv.w + g * cv.w;
      *(float4*)&out[off] = ov;
    }
  }
}

extern "C" void kernel_launch(void* const* d_in, const int* in_sizes, int n_in,
                              void* d_out, int out_size, void* d_ws, size_t ws_size,
                              hipStream_t stream) {
  const float* feat = (const float*)d_in[0];
  const float* Wd   = (const float*)d_in[1];
  const float* bd   = (const float*)d_in[2];
  const float* Wu   = (const float*)d_in[3];
  const float* bu   = (const float*)d_in[4];
  const float* mq   = (const float*)d_in[5];
  const float* lnw  = (const float*)d_in[6];
  const float* lnb  = (const float*)d_in[7];
  const float* inw  = (const float*)d_in[8];
  const float* inb  = (const float*)d_in[9];
  const float* ow   = (const float*)d_in[10];
  const float* ob   = (const float*)d_in[11];
  const float* gm   = (const float*)d_in[12];
  float* out = (float*)d_out;
  char* ws = (char*)d_ws;

  float* act    = (float*)(ws + 0);          // 16,777,216 B
  float* scores = (float*)(ws + 16777216);   //    262,144 B
  u16*   WdT    = (u16*)  (ws + 17039360);   //    131,072 B
  u16*   WuT    = (u16*)  (ws + 17170432);   //    131,072 B
  float* nq     = (float*)(ws + 17301504);   //      4,096 B
  int*   idx    = (int*)  (ws + 17305600);   //      4,096 B
  float* qkv    = (float*)(ws + 17309696);   //    983,040 B
  float* ao     = (float*)(ws + 18292736);   //    327,680 B  (total 18,620,416)

  hipLaunchKernelGGL(k0_prep,     dim3(257),  dim3(256), 0, stream, Wd, Wu, mq, WdT, WuT, nq);
  hipLaunchKernelGGL(k1_gemm_down,dim3(1024), dim3(256), 0, stream, feat, WdT, bd, nq, act, scores);
  hipLaunchKernelGGL(k2_topk,     dim3(16),   dim3(256), 0, stream, scores, idx);
  hipLaunchKernelGGL(k3a_ln_qkv,  dim3(16),   dim3(256), 0, stream, act, mq, idx, lnw, lnb, inw, inb, qkv);
  hipLaunchKernelGGL(k3b_attn,    dim3(64),   dim3(256), 0, stream, qkv, ao);
  hipLaunchKernelGGL(k3c_outproj, dim3(16),   dim3(256), 0, stream, ao, ow, ob, idx, act);
  hipLaunchKernelGGL(k4_gemm_up,  dim3(4096), dim3(256), 0, stream, act, WuT, feat, bu, gm, out);
}